// Round 1
// baseline (1310.295 us; speedup 1.0000x reference)
//
#include <hip/hip_runtime.h>
#include <math.h>

#define H 128
#define K 20
#define EPB 8   // edges per block (amortizes em_w1 reads x8)

// ---- workspace layout (float offsets) ----
#define WS_TBLP  0            // 129 rows x 128 d x {W,B} float2
#define WS_TBLN  33024        // 129 rows x 128 d x {W,B} float2
#define WS_THP   66048        // 128 sorted thresholds (pos-w1 group)
#define WS_THN   66176        // 128 sorted thresholds (neg-w1 group)
#define WS_BASE  66304        // 128: tp_b2 + zero-w1 active contrib
#define WS_CNT   66432        // 2 ints: nP, nN
#define WS_SIDXP 66434        // 128 ints: sorted original indices (P)
#define WS_SIDXN 66562        // 128 ints: sorted original indices (N)

// Kernel 1: classify h by sign(w1), sort thresholds -b1/w1 per group.
__global__ __launch_bounds__(128) void build_sort_kernel(
    const float* __restrict__ w1, const float* __restrict__ b1,
    const float* __restrict__ w2, const float* __restrict__ b2,
    float* __restrict__ ws)
{
  __shared__ float th[H];
  __shared__ int grp[H];
  __shared__ int nP_s, nN_s;
  int h = threadIdx.x;
  float w = w1[h], b = b1[h];
  int g = (w > 0.f) ? 0 : ((w < 0.f) ? 1 : 2);
  float t = (g == 2) ? 0.f : (-b / w);
  th[h] = t; grp[h] = g;
  if (h == 0) { nP_s = 0; nN_s = 0; }
  __syncthreads();
  int* sidxP = (int*)(ws + WS_SIDXP);
  int* sidxN = (int*)(ws + WS_SIDXN);
  if (g == 0) {
    int r = 0;
    for (int i = 0; i < H; i++)
      if (grp[i] == 0 && (th[i] < t || (th[i] == t && i < h))) r++;
    sidxP[r] = h; ws[WS_THP + r] = t;
    atomicAdd(&nP_s, 1);
  } else if (g == 1) {
    int r = 0;
    for (int i = 0; i < H; i++)
      if (grp[i] == 1 && (th[i] < t || (th[i] == t && i < h))) r++;
    sidxN[r] = h; ws[WS_THN + r] = t;
    atomicAdd(&nN_s, 1);
  }
  // BASE[d] = tp_b2[d] + sum over (w1==0, b1>0) of b1*w2[h][d]
  float base = b2[h];
  for (int i = 0; i < H; i++)
    if (grp[i] == 2 && b1[i] > 0.f) base += b1[i] * w2[i * H + h];
  ws[WS_BASE + h] = base;
  __syncthreads();
  if (h == 0) {
    ((int*)(ws + WS_CNT))[0] = nP_s;
    ((int*)(ws + WS_CNT))[1] = nN_s;
  }
}

// Kernel 2: one block per table row; recompute prefix/suffix sums
// independently per row (loads are independent -> pipelined, ~us total).
__global__ __launch_bounds__(128) void build_rows_kernel(
    const float* __restrict__ w1v, const float* __restrict__ b1v,
    const float* __restrict__ w2, float* __restrict__ ws)
{
  int r = blockIdx.x;       // 0..128 = P rows, 129..257 = N rows
  int d = threadIdx.x;
  const int* cnt = (const int*)(ws + WS_CNT);
  int nP = cnt[0], nN = cnt[1];
  if (r <= 128) {
    if (r > nP) return;
    const int* sidx = (const int*)(ws + WS_SIDXP);
    float accW = 0.f, accB = ws[WS_BASE + d];
    for (int i = 0; i < r; i++) {
      int idx = sidx[i];
      float wv = w2[idx * H + d];
      accW += w1v[idx] * wv;
      accB += b1v[idx] * wv;
    }
    ws[WS_TBLP + (r * H + d) * 2 + 0] = accW;
    ws[WS_TBLP + (r * H + d) * 2 + 1] = accB;
  } else {
    int rr = r - 129;
    if (rr > nN) return;
    const int* sidx = (const int*)(ws + WS_SIDXN);
    float accW = 0.f, accB = 0.f;
    for (int i = rr; i < nN; i++) {
      int idx = sidx[i];
      float wv = w2[idx * H + d];
      accW += w1v[idx] * wv;
      accB += b1v[idx] * wv;
    }
    ws[WS_TBLN + (rr * H + d) * 2 + 0] = accW;
    ws[WS_TBLN + (rr * H + d) * 2 + 1] = accB;
  }
}

// Main fused kernel: 256 threads = 2 sides x 128 dims; EPB edges per block.
__global__ __launch_bounds__(256) void tgat_main_kernel(
    const int* __restrict__ edge_index, const int* __restrict__ edge_ts,
    const int* __restrict__ hist_nb, const int* __restrict__ hist_tm,
    const int* __restrict__ hist_sg,
    const float* __restrict__ node_emb, const float* __restrict__ sign_emb,
    const float* __restrict__ em_w1, const float* __restrict__ em_b1,
    const float* __restrict__ em_w2, const float* __restrict__ em_b2,
    const float* __restrict__ ws, float* __restrict__ out, int B)
{
  __shared__ __align__(16) float feat[EPB][4 * H];
  __shared__ float hpart[2][EPB][H];
  __shared__ float thP_s[H], thN_s[H];
  __shared__ float red[2][2][K];
  __shared__ int nbuf[2][K], tbuf[2][K], sbuf[2][K];
  __shared__ int rbuf[2][2][K];
  __shared__ int cnt_s[2];

  int tid = threadIdx.x;
  int side = tid >> 7;        // 0 = u, 1 = v
  int d = tid & 127;
  int lane = tid & 63;
  int wv = (tid >> 6) & 1;    // wave within side

  if (tid < H) thP_s[tid] = ws[WS_THP + tid];
  else         thN_s[tid - H] = ws[WS_THN + tid - H];
  if (tid == 0) {
    cnt_s[0] = ((const int*)(ws + WS_CNT))[0];
    cnt_s[1] = ((const int*)(ws + WS_CNT))[1];
  }
  __syncthreads();
  int nP = cnt_s[0], nN = cnt_s[1];

  const float2* tblP = (const float2*)(ws + WS_TBLP);
  const float2* tblN = (const float2*)(ws + WS_TBLN);

  int b0 = blockIdx.x * EPB;

  for (int e = 0; e < EPB; e++) {
    int b = b0 + e;
    if (b < B) {   // uniform across block
      int node = edge_index[side * B + b];
      int t = edge_ts[b];
      float q = node_emb[node * H + d];
      if (d < K) {
        int nb = hist_nb[node * K + d];
        int tm = hist_tm[node * K + d];
        int sg = hist_sg[node * K + d];
        nbuf[side][d] = nb; tbuf[side][d] = tm; sbuf[side][d] = sg;
        float delta = (float)t - (float)tm;
        int lo = 0, hi = nP;
        while (lo < hi) { int m = (lo + hi) >> 1; if (thP_s[m] < delta) lo = m + 1; else hi = m; }
        rbuf[side][0][d] = lo;
        lo = 0; hi = nN;
        while (lo < hi) { int m = (lo + hi) >> 1; if (thN_s[m] < delta) lo = m + 1; else hi = m; }
        rbuf[side][1][d] = lo;
      }
      __syncthreads();   // (A)

      float key[K];
      #pragma unroll
      for (int k = 0; k < K; k++) {
        int nb = nbuf[side][k];
        int nbc = (nb < 0) ? 0 : nb;
        int sg = sbuf[side][k];
        float delta = (float)t - (float)tbuf[side][k];
        float2 pw = tblP[rbuf[side][0][k] * H + d];
        float2 nw = tblN[rbuf[side][1][k] * H + d];
        float te = delta * (pw.x + nw.x) + (pw.y + nw.y);
        float kv = node_emb[nbc * H + d] + sign_emb[sg * H + d] + te;
        key[k] = kv;
        float p = q * kv;
        #pragma unroll
        for (int off = 32; off > 0; off >>= 1) p += __shfl_down(p, off, 64);
        if (lane == 0) red[side][wv][k] = p;
      }
      __syncthreads();   // (B)

      float s[K];
      float mx = -3.0e38f;
      #pragma unroll
      for (int k = 0; k < K; k++) {
        float sc = (red[side][0][k] + red[side][1][k]) * 0.088388347648318447f; // 1/sqrt(128)
        bool valid = (nbuf[side][k] != -1) && (tbuf[side][k] < t);
        sc = valid ? sc : -1e9f;
        s[k] = sc;
        mx = fmaxf(mx, sc);
      }
      float ssum = 0.f;
      #pragma unroll
      for (int k = 0; k < K; k++) { float ev = __expf(s[k] - mx); s[k] = ev; ssum += ev; }
      float inv = 1.f / ssum;
      float z = 0.f;
      #pragma unroll
      for (int k = 0; k < K; k++) z += (s[k] * inv) * key[k];
      feat[e][side * H + d] = z;
      __syncthreads();   // (C)
      if (side == 0) feat[e][2 * H + d] = fabsf(feat[e][d] - feat[e][H + d]);
      else           feat[e][3 * H + d] = feat[e][d] * feat[e][H + d];
    }
  }
  __syncthreads();

  // ---- final MLP: hid = relu(feat @ em_w1 + em_b1); logit = hid @ em_w2 + em_b2
  // thread (side,d): partial over i in [side*256, side*256+256) for output dim d,
  // all EPB edges at once (em_w1 value reused x8 from a register).
  float acc[EPB];
  #pragma unroll
  for (int e = 0; e < EPB; e++) acc[e] = 0.f;
  int ibase = side * 2 * H;
  for (int ii = 0; ii < 2 * H; ii += 4) {
    float w0 = em_w1[(ibase + ii + 0) * H + d];
    float w1_ = em_w1[(ibase + ii + 1) * H + d];
    float w2_ = em_w1[(ibase + ii + 2) * H + d];
    float w3_ = em_w1[(ibase + ii + 3) * H + d];
    #pragma unroll
    for (int e = 0; e < EPB; e++) {
      float4 f = *(const float4*)&feat[e][ibase + ii];   // uniform addr -> LDS broadcast
      acc[e] += f.x * w0 + f.y * w1_ + f.z * w2_ + f.w * w3_;
    }
  }
  #pragma unroll
  for (int e = 0; e < EPB; e++) hpart[side][e][d] = acc[e];
  __syncthreads();

  // each wave (4 total) finishes 2 edges
  int w4 = tid >> 6;
  #pragma unroll
  for (int ei = 0; ei < 2; ei++) {
    int e = w4 * 2 + ei;
    int b = b0 + e;
    float h0 = hpart[0][e][lane]      + hpart[1][e][lane]      + em_b1[lane];
    float h1 = hpart[0][e][lane + 64] + hpart[1][e][lane + 64] + em_b1[lane + 64];
    h0 = fmaxf(h0, 0.f); h1 = fmaxf(h1, 0.f);
    float p = h0 * em_w2[lane] + h1 * em_w2[lane + 64];
    #pragma unroll
    for (int off = 32; off > 0; off >>= 1) p += __shfl_down(p, off, 64);
    if (lane == 0 && b < B) out[b] = p + em_b2[0];
  }
}

extern "C" void kernel_launch(void* const* d_in, const int* in_sizes, int n_in,
                              void* d_out, int out_size, void* d_ws, size_t ws_size,
                              hipStream_t stream)
{
  (void)n_in; (void)out_size; (void)ws_size;
  const int* edge_index = (const int*)d_in[0];
  const int* edge_ts    = (const int*)d_in[1];
  const int* hist_nb    = (const int*)d_in[2];
  const int* hist_tm    = (const int*)d_in[3];
  const int* hist_sg    = (const int*)d_in[4];
  const float* node_emb = (const float*)d_in[5];
  const float* sign_emb = (const float*)d_in[6];
  const float* tp_w1    = (const float*)d_in[7];
  const float* tp_b1    = (const float*)d_in[8];
  const float* tp_w2    = (const float*)d_in[9];
  const float* tp_b2    = (const float*)d_in[10];
  const float* em_w1    = (const float*)d_in[11];
  const float* em_b1    = (const float*)d_in[12];
  const float* em_w2    = (const float*)d_in[13];
  const float* em_b2    = (const float*)d_in[14];
  float* out = (float*)d_out;
  float* ws  = (float*)d_ws;
  int B = in_sizes[1];

  hipLaunchKernelGGL(build_sort_kernel, dim3(1), dim3(H), 0, stream,
                     tp_w1, tp_b1, tp_w2, tp_b2, ws);
  hipLaunchKernelGGL(build_rows_kernel, dim3(258), dim3(H), 0, stream,
                     tp_w1, tp_b1, tp_w2, ws);
  int grid = (B + EPB - 1) / EPB;
  hipLaunchKernelGGL(tgat_main_kernel, dim3(grid), dim3(256), 0, stream,
                     edge_index, edge_ts, hist_nb, hist_tm, hist_sg,
                     node_emb, sign_emb, em_w1, em_b1, em_w2, em_b2, ws, out, B);
}

// Round 2
// 695.666 us; speedup vs baseline: 1.8835x; 1.8835x over previous
//
#include <hip/hip_runtime.h>
#include <math.h>

#define H 128
#define K 20
#define EPB 8   // edges per block (amortizes em_w1 reads x8)

// ---- workspace layout (float offsets) ----
#define WS_TBLP  0            // 129 rows x 128 d x {W,B} float2
#define WS_TBLN  33024        // 129 rows x 128 d x {W,B} float2
#define WS_THP   66048        // 128 sorted thresholds (pos-w1 group)
#define WS_THN   66176        // 128 sorted thresholds (neg-w1 group)
#define WS_BASE  66304        // 128: tp_b2 + zero-w1 active contrib
#define WS_CNT   66432        // 2 ints: nP, nN
#define WS_SIDXP 66434        // 128 ints: sorted original indices (P)
#define WS_SIDXN 66562        // 128 ints: sorted original indices (N)

// Kernel 1: classify h by sign(w1), sort thresholds -b1/w1 per group.
__global__ __launch_bounds__(128) void build_sort_kernel(
    const float* __restrict__ w1, const float* __restrict__ b1,
    const float* __restrict__ w2, const float* __restrict__ b2,
    float* __restrict__ ws)
{
  __shared__ float th[H];
  __shared__ int grp[H];
  __shared__ int nP_s, nN_s;
  int h = threadIdx.x;
  float w = w1[h], b = b1[h];
  int g = (w > 0.f) ? 0 : ((w < 0.f) ? 1 : 2);
  float t = (g == 2) ? 0.f : (-b / w);
  th[h] = t; grp[h] = g;
  if (h == 0) { nP_s = 0; nN_s = 0; }
  __syncthreads();
  int* sidxP = (int*)(ws + WS_SIDXP);
  int* sidxN = (int*)(ws + WS_SIDXN);
  if (g == 0) {
    int r = 0;
    for (int i = 0; i < H; i++)
      if (grp[i] == 0 && (th[i] < t || (th[i] == t && i < h))) r++;
    sidxP[r] = h; ws[WS_THP + r] = t;
    atomicAdd(&nP_s, 1);
  } else if (g == 1) {
    int r = 0;
    for (int i = 0; i < H; i++)
      if (grp[i] == 1 && (th[i] < t || (th[i] == t && i < h))) r++;
    sidxN[r] = h; ws[WS_THN + r] = t;
    atomicAdd(&nN_s, 1);
  }
  // BASE[d] = tp_b2[d] + sum over (w1==0, b1>0) of b1*w2[h][d]
  float base = b2[h];
  for (int i = 0; i < H; i++)
    if (grp[i] == 2 && b1[i] > 0.f) base += b1[i] * w2[i * H + h];
  ws[WS_BASE + h] = base;
  __syncthreads();
  if (h == 0) {
    ((int*)(ws + WS_CNT))[0] = nP_s;
    ((int*)(ws + WS_CNT))[1] = nN_s;
  }
}

// Kernel 2: one block per table row; prefix/suffix sums per row.
__global__ __launch_bounds__(128) void build_rows_kernel(
    const float* __restrict__ w1v, const float* __restrict__ b1v,
    const float* __restrict__ w2, float* __restrict__ ws)
{
  int r = blockIdx.x;       // 0..128 = P rows, 129..257 = N rows
  int d = threadIdx.x;
  const int* cnt = (const int*)(ws + WS_CNT);
  int nP = cnt[0], nN = cnt[1];
  if (r <= 128) {
    if (r > nP) return;
    const int* sidx = (const int*)(ws + WS_SIDXP);
    float accW = 0.f, accB = ws[WS_BASE + d];
    for (int i = 0; i < r; i++) {
      int idx = sidx[i];
      float wv = w2[idx * H + d];
      accW += w1v[idx] * wv;
      accB += b1v[idx] * wv;
    }
    ws[WS_TBLP + (r * H + d) * 2 + 0] = accW;
    ws[WS_TBLP + (r * H + d) * 2 + 1] = accB;
  } else {
    int rr = r - 129;
    if (rr > nN) return;
    const int* sidx = (const int*)(ws + WS_SIDXN);
    float accW = 0.f, accB = 0.f;
    for (int i = rr; i < nN; i++) {
      int idx = sidx[i];
      float wv = w2[idx * H + d];
      accW += w1v[idx] * wv;
      accB += b1v[idx] * wv;
    }
    ws[WS_TBLN + (rr * H + d) * 2 + 0] = accW;
    ws[WS_TBLN + (rr * H + d) * 2 + 1] = accB;
  }
}

// Main fused kernel: 4 waves per block; each wave owns an edge-side
// end-to-end (lane holds dims d and d+64). Zero barriers until the MLP.
__global__ __launch_bounds__(256) void tgat_main_kernel(
    const int* __restrict__ edge_index, const int* __restrict__ edge_ts,
    const int* __restrict__ hist_nb, const int* __restrict__ hist_tm,
    const int* __restrict__ hist_sg,
    const float* __restrict__ node_emb, const float* __restrict__ sign_emb,
    const float* __restrict__ em_w1, const float* __restrict__ em_b1,
    const float* __restrict__ em_w2, const float* __restrict__ em_b2,
    const float* __restrict__ ws, float* __restrict__ out, int B)
{
  __shared__ __align__(16) float feat[EPB][4 * H];
  __shared__ float hpart[2][EPB][H];

  int tid = threadIdx.x;
  int lane = tid & 63;
  int wv = tid >> 6;            // wave 0..3
  int b0 = blockIdx.x * EPB;

  const int* cnt = (const int*)(ws + WS_CNT);
  int nP = cnt[0], nN = cnt[1];
  // thresholds in registers (masked by group count; rank via ballot-count)
  float thP0 = (lane      < nP) ? ws[WS_THP + lane]      : 3.0e38f;
  float thP1 = (lane + 64 < nP) ? ws[WS_THP + lane + 64] : 3.0e38f;
  float thN0 = (lane      < nN) ? ws[WS_THN + lane]      : 3.0e38f;
  float thN1 = (lane + 64 < nN) ? ws[WS_THN + lane + 64] : 3.0e38f;
  // sign embedding rows in registers
  float se00 = sign_emb[lane],     se01 = sign_emb[lane + 64];
  float se10 = sign_emb[H + lane], se11 = sign_emb[H + lane + 64];

  const float2* tblP = (const float2*)(ws + WS_TBLP);
  const float2* tblN = (const float2*)(ws + WS_TBLN);

  #pragma unroll 1
  for (int i = 0; i < (2 * EPB) / 4; i++) {
    int s = wv * ((2 * EPB) / 4) + i;   // edge-side id within block
    int e = s >> 1, side = s & 1;
    int b = b0 + e;
    if (b < B) {                        // wave-uniform
      int node = edge_index[side * B + b];
      int t = edge_ts[b];
      float q0 = node_emb[node * H + lane];
      float q1 = node_emb[node * H + lane + 64];
      int pk_r = 0, tm_r = 0;
      if (lane < K) {
        int nb = hist_nb[node * K + lane];
        int sg = hist_sg[node * K + lane];
        tm_r = hist_tm[node * K + lane];
        pk_r = (nb << 1) | sg;          // pack neighbor id + sign
      }
      float key0[K], key1[K], sc[K];
      #pragma unroll
      for (int k = 0; k < K; k++) {
        int tm_k = __shfl(tm_r, k, 64);
        int pk_k = __shfl(pk_r, k, 64);
        int nb_k = pk_k >> 1;
        int sg_k = pk_k & 1;
        float dk = (float)t - (float)tm_k;
        int rP = __popcll(__ballot(thP0 < dk)) + __popcll(__ballot(thP1 < dk));
        int rN = __popcll(__ballot(thN0 < dk)) + __popcll(__ballot(thN1 < dk));
        float2 pw0 = tblP[rP * H + lane];
        float2 pw1 = tblP[rP * H + lane + 64];
        float2 nw0 = tblN[rN * H + lane];
        float2 nw1 = tblN[rN * H + lane + 64];
        int nbc = (nb_k < 0) ? 0 : nb_k;
        float ne0 = node_emb[nbc * H + lane];
        float ne1 = node_emb[nbc * H + lane + 64];
        float te0 = dk * (pw0.x + nw0.x) + (pw0.y + nw0.y);
        float te1 = dk * (pw1.x + nw1.x) + (pw1.y + nw1.y);
        float k0 = ne0 + (sg_k ? se10 : se00) + te0;
        float k1 = ne1 + (sg_k ? se11 : se01) + te1;
        key0[k] = k0; key1[k] = k1;
        float p = q0 * k0 + q1 * k1;
        #pragma unroll
        for (int off = 1; off < 64; off <<= 1) p += __shfl_xor(p, off, 64);
        bool valid = (nb_k != -1) && (tm_k < t);
        sc[k] = valid ? p * 0.088388347648318447f : -1e9f;  // 1/sqrt(128)
      }
      float mx = sc[0];
      #pragma unroll
      for (int k = 1; k < K; k++) mx = fmaxf(mx, sc[k]);
      float ssum = 0.f;
      #pragma unroll
      for (int k = 0; k < K; k++) { float ev = __expf(sc[k] - mx); sc[k] = ev; ssum += ev; }
      float inv = 1.f / ssum;
      float z0 = 0.f, z1 = 0.f;
      #pragma unroll
      for (int k = 0; k < K; k++) {
        float a = sc[k] * inv;
        z0 += a * key0[k];
        z1 += a * key1[k];
      }
      feat[e][side * H + lane]      = z0;
      feat[e][side * H + lane + 64] = z1;
    }
  }
  __syncthreads();

  // derived feature columns: |zu-zv|, zu*zv
  for (int j = tid; j < EPB * H; j += 256) {
    int e = j >> 7, d = j & 127;
    float a = feat[e][d], c = feat[e][H + d];
    feat[e][2 * H + d] = fabsf(a - c);
    feat[e][3 * H + d] = a * c;
  }
  __syncthreads();

  // ---- final MLP: hid = relu(feat @ em_w1 + em_b1); logit = hid @ em_w2 + em_b2
  // thread (half,d): partial over i in [half*256, half*256+256) for output dim d,
  // all EPB edges at once (em_w1 value reused x8 from a register).
  int half = tid >> 7;
  int d = tid & 127;
  float acc[EPB];
  #pragma unroll
  for (int e = 0; e < EPB; e++) acc[e] = 0.f;
  int ibase = half * 2 * H;
  for (int ii = 0; ii < 2 * H; ii += 4) {
    float w0 = em_w1[(ibase + ii + 0) * H + d];
    float w1_ = em_w1[(ibase + ii + 1) * H + d];
    float w2_ = em_w1[(ibase + ii + 2) * H + d];
    float w3_ = em_w1[(ibase + ii + 3) * H + d];
    #pragma unroll
    for (int e = 0; e < EPB; e++) {
      float4 f = *(const float4*)&feat[e][ibase + ii];   // uniform addr -> LDS broadcast
      acc[e] += f.x * w0 + f.y * w1_ + f.z * w2_ + f.w * w3_;
    }
  }
  #pragma unroll
  for (int e = 0; e < EPB; e++) hpart[half][e][d] = acc[e];
  __syncthreads();

  // each wave (4 total) finishes 2 edges
  #pragma unroll
  for (int ei = 0; ei < 2; ei++) {
    int e = wv * 2 + ei;
    int b = b0 + e;
    float h0 = hpart[0][e][lane]      + hpart[1][e][lane]      + em_b1[lane];
    float h1 = hpart[0][e][lane + 64] + hpart[1][e][lane + 64] + em_b1[lane + 64];
    h0 = fmaxf(h0, 0.f); h1 = fmaxf(h1, 0.f);
    float p = h0 * em_w2[lane] + h1 * em_w2[lane + 64];
    #pragma unroll
    for (int off = 32; off > 0; off >>= 1) p += __shfl_down(p, off, 64);
    if (lane == 0 && b < B) out[b] = p + em_b2[0];
  }
}

extern "C" void kernel_launch(void* const* d_in, const int* in_sizes, int n_in,
                              void* d_out, int out_size, void* d_ws, size_t ws_size,
                              hipStream_t stream)
{
  (void)n_in; (void)out_size; (void)ws_size;
  const int* edge_index = (const int*)d_in[0];
  const int* edge_ts    = (const int*)d_in[1];
  const int* hist_nb    = (const int*)d_in[2];
  const int* hist_tm    = (const int*)d_in[3];
  const int* hist_sg    = (const int*)d_in[4];
  const float* node_emb = (const float*)d_in[5];
  const float* sign_emb = (const float*)d_in[6];
  const float* tp_w1    = (const float*)d_in[7];
  const float* tp_b1    = (const float*)d_in[8];
  const float* tp_w2    = (const float*)d_in[9];
  const float* tp_b2    = (const float*)d_in[10];
  const float* em_w1    = (const float*)d_in[11];
  const float* em_b1    = (const float*)d_in[12];
  const float* em_w2    = (const float*)d_in[13];
  const float* em_b2    = (const float*)d_in[14];
  float* out = (float*)d_out;
  float* ws  = (float*)d_ws;
  int B = in_sizes[1];

  hipLaunchKernelGGL(build_sort_kernel, dim3(1), dim3(H), 0, stream,
                     tp_w1, tp_b1, tp_w2, tp_b2, ws);
  hipLaunchKernelGGL(build_rows_kernel, dim3(258), dim3(H), 0, stream,
                     tp_w1, tp_b1, tp_w2, ws);
  int grid = (B + EPB - 1) / EPB;
  hipLaunchKernelGGL(tgat_main_kernel, dim3(grid), dim3(256), 0, stream,
                     edge_index, edge_ts, hist_nb, hist_tm, hist_sg,
                     node_emb, sign_emb, em_w1, em_b1, em_w2, em_b2, ws, out, B);
}